// Round 8
// baseline (114.258 us; speedup 1.0000x reference)
//
#include <hip/hip_runtime.h>
#include <math.h>

#define N_G 512
#define IMG_H 324
#define IMG_W 332
#define N_C 120
#define HW (IMG_H*IMG_W)
#define CHUNK 48               // <=64 (ull liveness bitmask); 4 blocks/CU
#define TSX 21                 // tiles in x (16 px)
#define TSY 81                 // tiles in y (4 px)
#define NT (TSX*TSY)
#define NBLK (NT*4)            // 4 channel-split blocks per tile

// Round-7 structure (best: 111.7us total, k_render ~23us) + two conservative
// work cuts:
//  (1) build-time ellipse nearest-point prune: clamp center to tile box,
//      emax = l2op - (c00 dx^2 + c11 dy^2) upper-bounds e at EVERY pixel
//      (separable quadratic minimized at clamp), so emax <= -24 rows are
//      exactly those phase A would ballot dead. ~25-30% fewer nh.
//  (2) mid-chunk early stop: every 16 live hits, uniform ballot T>=1e-5.
//      T is bitwise-identical across waves -> all waves break together;
//      same remainder<=T error bound as the chunk-end check, finer grain.

__global__ __launch_bounds__(256, 4) void k_render(
    const float* __restrict__ pos, const float* __restrict__ scales,
    const float* __restrict__ opac, const float* __restrict__ Km,
    const float* __restrict__ Em, const float* __restrict__ spec,
    const float* __restrict__ tm, float* __restrict__ out)
{
  __shared__ __align__(16) float prm[N_G*8];     // rank-sorted hit params (16 KB)
  __shared__ __align__(16) float buf[CHUNK*64];  // keys during build; alpha (12 KB)
  __shared__ __align__(16) float sbuf[CHUNK*32]; // staged 30-ch rows (6 KB)
  __shared__ unsigned long long livem[4];
  __shared__ int wcnt[4];
  // total ~35 KB -> 4 blocks/CU (16 waves/CU)

  const int tid  = threadIdx.x;
  const int w    = tid >> 6;
  const int lane = tid & 63;
  const int tx = lane & 15, ty = lane >> 4;
  const unsigned long long ltm = (1ull << lane) - 1ull;

  const int t  = blockIdx.x >> 2;       // tile
  const int cq = blockIdx.x & 3;        // channel quarter

  // ---- prep: project 2 gaussians per thread into registers ----
  float psx[2], psy[2], pc00[2], pc11[2], pl2[2], pd[2];
  float bxmin[2], bxmax[2], bymin[2], bymax[2];
  {
    const float E0=Em[0],E1=Em[1],E2=Em[2],E3=Em[3],
                E4=Em[4],E5=Em[5],E6=Em[6],E7=Em[7],
                E8=Em[8],E9=Em[9],E10=Em[10],E11=Em[11];
    const float K0=Km[0],K1=Km[1],K2=Km[2],
                K3=Km[3],K4=Km[4],K5=Km[5],
                K6=Km[6],K7=Km[7],K8=Km[8];
    #pragma unroll
    for (int q = 0; q < 2; ++q) {
      const int g = w*128 + lane + q*64;           // original index (wave-major)
      float p0 = pos[g*3+0], p1 = pos[g*3+1], p2 = pos[g*3+2];
      float cam0 = E0*p0 + E1*p1 + E2*p2  + E3;
      float cam1 = E4*p0 + E5*p1 + E6*p2  + E7;
      float cam2 = E8*p0 + E9*p1 + E10*p2 + E11;
      float pr0 = K0*cam0 + K1*cam1 + K2*cam2;
      float pr1 = K3*cam0 + K4*cam1 + K5*cam2;
      float pr2 = K6*cam0 + K7*cam1 + K8*cam2;
      float inv = 1.0f/(pr2 + 1e-6f);
      float sx = pr0*inv, sy = pr1*inv;
      float depth = cam2;
      bool valid = (depth > 0.01f) && (depth < 100.0f)
                && (sx > -100.0f) && (sx < (float)IMG_W + 100.0f)
                && (sy > -100.0f) && (sy < (float)IMG_H + 100.0f);
      bool off = (sx < -(float)IMG_W) || (sx > 2.0f*(float)IMG_W)
              || (sy < -(float)IMG_H) || (sy > 2.0f*(float)IMG_H);
      bool skip = off || (!valid);
      float s0 = scales[g*3+0], s1 = scales[g*3+1];
      float v0 = s0*s0 + 1e-4f, v1 = s1*s1 + 1e-4f;
      const float HL2E = 0.72134752f;              // 0.5*log2(e)
      psx[q] = sx; psy[q] = sy;
      pc00[q] = HL2E/v0; pc11[q] = HL2E/v1;
      pl2[q] = __log2f(skip ? 0.0f : opac[g]);     // op=0 -> -inf -> exp2 -> 0
      pd[q]  = depth;
      float rx = 6.0f*sqrtf(v0);                   // mahal cutoff 36 (6 sigma)
      float ry = 6.0f*sqrtf(v1);
      bxmin[q] = skip ?  1e9f : sx - rx;
      bxmax[q] = skip ? -1e9f : sx + rx;
      bymin[q] = skip ?  1e9f : sy - ry;
      bymax[q] = skip ? -1e9f : sy + ry;
    }
  }

  // center-out bijection: heavy central tiles get the lowest blockIdx
  const int jx = t % TSX, ky = t / TSX;
  const int bx = 10 + ((jx & 1) ? ((jx+1)>>1) : -((jx+1)>>1));
  const int by = 40 + ((ky & 1) ? ((ky+1)>>1) : -((ky+1)>>1));

  const int x = bx*16 + tx;
  const int y = by*4 + ty;
  const bool inb = (x < IMG_W) && (y < IMG_H);
  const float px = (float)min(x, IMG_W-1);
  const float py = (float)min(y, IMG_H-1);
  const float wxmin = (float)(bx*16), wxmax = wxmin + 15.0f;
  const float wymin = (float)(by*4),  wymax = wymin + 3.0f;

  // ---- build: AABB + ellipse nearest-point prune, compaction, rank-sort ----
  bool h0 = !(bxmin[0] > wxmax || bxmax[0] < wxmin ||
              bymin[0] > wymax || bymax[0] < wymin);
  bool h1 = !(bxmin[1] > wxmax || bxmax[1] < wxmin ||
              bymin[1] > wymax || bymax[1] < wymin);
  {
    // nearest point of tile box to center; emax bounds e over all pixels
    float nx0 = fminf(fmaxf(psx[0], wxmin), wxmax);
    float ny0 = fminf(fmaxf(psy[0], wymin), wymax);
    float dx0 = nx0 - psx[0], dy0 = ny0 - psy[0];
    h0 = h0 && (pl2[0] - (pc00[0]*dx0*dx0 + pc11[0]*dy0*dy0) > -24.0f);
    float nx1 = fminf(fmaxf(psx[1], wxmin), wxmax);
    float ny1 = fminf(fmaxf(psy[1], wymin), wymax);
    float dx1 = nx1 - psx[1], dy1 = ny1 - psy[1];
    h1 = h1 && (pl2[1] - (pc00[1]*dx1*dx1 + pc11[1]*dy1*dy1) > -24.0f);
  }
  unsigned long long m0 = __ballot(h0), m1 = __ballot(h1);
  int c0 = __popcll(m0);
  if (lane == 0) wcnt[w] = c0 + __popcll(m1);
  __syncthreads();
  int offw = 0;
  #pragma unroll
  for (int k = 0; k < 4; ++k) if (k < w) offw += wcnt[k];
  const int nh = wcnt[0] + wcnt[1] + wcnt[2] + wcnt[3];
  // compacted depth keys (compaction order == original-index order)
  const int p0 = offw + __popcll(m0 & ltm);
  const int p1 = offw + c0 + __popcll(m1 & ltm);
  if (h0) buf[p0] = pd[0];
  if (h1) buf[p1] = pd[1];
  if (tid < 4) buf[nh + tid] = 1e30f;            // pad for float4 scan
  __syncthreads();

  // rank-scan (broadcast b128 reads); stable tie-break by compacted position
  if (h0 | h1) {
    int r0 = 0, r1 = 0;
    const float d0 = pd[0], d1 = pd[1];
    for (int j = 0; j < nh; j += 4) {
      float4 k4 = *(const float4*)&buf[j];
      if (h0) {
        r0 += (k4.x < d0 || (k4.x == d0 && j+0 < p0)) ? 1 : 0;
        r0 += (k4.y < d0 || (k4.y == d0 && j+1 < p0)) ? 1 : 0;
        r0 += (k4.z < d0 || (k4.z == d0 && j+2 < p0)) ? 1 : 0;
        r0 += (k4.w < d0 || (k4.w == d0 && j+3 < p0)) ? 1 : 0;
      }
      if (h1) {
        r1 += (k4.x < d1 || (k4.x == d1 && j+0 < p1)) ? 1 : 0;
        r1 += (k4.y < d1 || (k4.y == d1 && j+1 < p1)) ? 1 : 0;
        r1 += (k4.z < d1 || (k4.z == d1 && j+2 < p1)) ? 1 : 0;
        r1 += (k4.w < d1 || (k4.w == d1 && j+3 < p1)) ? 1 : 0;
      }
    }
    if (h0) {
      *(float4*)&prm[r0*8]   = make_float4(psx[0], psy[0], pc00[0], pc11[0]);
      *(float4*)&prm[r0*8+4] = make_float4(pl2[0], pd[0],
                                 __int_as_float((w*128 + lane)*N_C), 0.0f);
    }
    if (h1) {
      *(float4*)&prm[r1*8]   = make_float4(psx[1], psy[1], pc00[1], pc11[1]);
      *(float4*)&prm[r1*8+4] = make_float4(pl2[1], pd[1],
                                 __int_as_float((w*128 + lane + 64)*N_C), 0.0f);
    }
  }
  __syncthreads();

  float T = 1.0f, dacc = 0.0f;          // T bitwise-identical across waves
  float4 acc0 = {0,0,0,0}, acc1 = {0,0,0,0};   // groups g0 = cq+8w, g1 = g0+4
  const int g0 = cq + 8*w;
  const bool g1ok = (g0 + 4) < 30;
  // staging channel for lanes < 32: c = 16*(lane>>2) + 4*cq + (lane&3)
  const int stc = 16*(lane >> 2) + 4*cq + (lane & 3);
  const bool stok = (lane < 32) && (stc < N_C);

  bool sat = false;
  for (int cb = 0; cb < nh && !sat; cb += CHUNK) {
    const int nc = min(CHUNK, nh - cb);

    // ---- phase A: alpha + liveness ballot + 30-ch staging (live rows) ----
    unsigned long long lm = 0;
    #pragma unroll 2
    for (int j = w; j < nc; j += 4) {
      float4 q0 = *(const float4*)&prm[(cb+j)*8];     // ds_read_b128
      float4 q1 = *(const float4*)&prm[(cb+j)*8+4];
      float dx = px - q0.x, dy = py - q0.y;
      float m = q0.z*dx*dx + q0.w*dy*dy;              // log2-units
      float e = q1.x - m;
      buf[j*64 + lane] = exp2f(e);                    // raw alpha
      unsigned long long bl = __ballot(e > -24.0f);   // alpha >= ~6e-8 anywhere?
      if (bl) {
        lm |= 1ull << j;
        int sbase = __float_as_int(q1.z);             // src*120
        if (stok) sbuf[j*32 + lane] = spec[sbase + stc];
      }
    }
    if (lane == 0) livem[w] = lm;
    __syncthreads();
    const unsigned long long mask = livem[0]|livem[1]|livem[2]|livem[3];

    // ---- phase B: per-wave fused T-chain + channel accumulation ----
    unsigned long long m2 = mask;
    int cnt = 0;
    while (m2) {
      const int j = __builtin_ctzll(m2); m2 &= m2 - 1;
      float a  = buf[j*64 + lane];                    // conflict-free b32
      float wv = a * T;
      T *= (1.0f - a);
      if (w == 0)                                     // wave-uniform branch
        dacc = fmaf(prm[(cb+j)*8+5], wv, dacc);       // depth (used by cq2)
      const float* row = &sbuf[j*32 + 8*w];           // uniform b128 reads
      float4 s0 = *(const float4*)(row);
      acc0.x = fmaf(wv, s0.x, acc0.x);
      acc0.y = fmaf(wv, s0.y, acc0.y);
      acc0.z = fmaf(wv, s0.z, acc0.z);
      acc0.w = fmaf(wv, s0.w, acc0.w);
      if (g1ok) {
        float4 s1 = *(const float4*)(row + 4);
        acc1.x = fmaf(wv, s1.x, acc1.x);
        acc1.y = fmaf(wv, s1.y, acc1.y);
        acc1.z = fmaf(wv, s1.z, acc1.z);
        acc1.w = fmaf(wv, s1.w, acc1.w);
      }
      // mid-chunk early stop: T identical across waves -> uniform break
      if ((++cnt & 15) == 0) {
        if (!__ballot(T >= 1e-5f)) { sat = true; break; }
      }
    }
    __syncthreads();   // all waves reach (identical control flow); buf reuse
    if (!sat && !__ballot(T >= 1e-5f)) sat = true;  // chunk-end check
  }

  // ---- epilogue: store wave-exclusive channel groups (no combine) ----
  if (inb) {
    const int pixi = y*IMG_W + x;
    const float bgT = T;                // BG*(1 - A_final), BG = 1.0
    float4 t0 = *(const float4*)&tm[4*g0];
    out[(4*g0+0)*HW + pixi] = (acc0.x + bgT)*t0.x;
    out[(4*g0+1)*HW + pixi] = (acc0.y + bgT)*t0.y;
    out[(4*g0+2)*HW + pixi] = (acc0.z + bgT)*t0.z;
    out[(4*g0+3)*HW + pixi] = (acc0.w + bgT)*t0.w;
    if (g1ok) {
      const int g1 = g0 + 4;
      float4 t1 = *(const float4*)&tm[4*g1];
      out[(4*g1+0)*HW + pixi] = (acc1.x + bgT)*t1.x;
      out[(4*g1+1)*HW + pixi] = (acc1.y + bgT)*t1.y;
      out[(4*g1+2)*HW + pixi] = (acc1.z + bgT)*t1.z;
      out[(4*g1+3)*HW + pixi] = (acc1.w + bgT)*t1.w;
    }
    if (cq == 2 && w == 0) out[N_C*HW + pixi] = dacc;          // depth
    if (cq == 3 && w == 0) out[N_C*HW + HW + pixi] = 1.0f - T; // A_final
  }
}

extern "C" void kernel_launch(void* const* d_in, const int* in_sizes, int n_in,
                              void* d_out, int out_size, void* d_ws, size_t ws_size,
                              hipStream_t stream) {
  const float* pos    = (const float*)d_in[0];
  // d_in[1] rotations: unused by the reference
  const float* scales = (const float*)d_in[2];
  const float* opac   = (const float*)d_in[3];
  const float* spec   = (const float*)d_in[4];
  const float* tm     = (const float*)d_in[5];
  const float* K      = (const float*)d_in[6];
  const float* E      = (const float*)d_in[7];
  float* out = (float*)d_out;
  (void)d_ws; (void)ws_size;   // no workspace needed

  k_render<<<NBLK, 256, 0, stream>>>(pos, scales, opac, K, E, spec, tm, out);
}

// Round 9
// 113.586 us; speedup vs baseline: 1.0059x; 1.0059x over previous
//
#include <hip/hip_runtime.h>
#include <math.h>

#define N_G 512
#define IMG_H 324
#define IMG_W 332
#define N_C 120
#define HW (IMG_H*IMG_W)
#define CHUNK 48               // <=64 (ull liveness bitmask); 4 blocks/CU
#define TSX 21                 // tiles in x (16 px)
#define TSY 81                 // tiles in y (4 px)
#define NT (TSX*TSY)
#define NBLK (NT*4)            // 4 channel-split blocks per tile

// Round-7 structure (best clean kernel: 111.7us total, k_render ~23us)
// + round-8's build-time ellipse nearest-point prune ONLY.
// Round-8's mid-chunk ballot is REVERTED: the per-iteration counter +
// cross-lane ballot + data-dependent break inside phase B's hot loop broke
// unrolling/pipelining (VALUBusy 45->52%, k_render 23->43us). Lesson: keep
// the inner loop branch-free; check saturation only at chunk end.
// Prune correctness: clamping the center to the tile box minimizes the
// separable quadratic over the box, so emax = l2op - (c00 dx^2 + c11 dy^2)
// upper-bounds e at every pixel; emax <= -24 rows are exactly the rows
// phase A's liveness ballot would mark dead -> output bit-identical.

__global__ __launch_bounds__(256, 4) void k_render(
    const float* __restrict__ pos, const float* __restrict__ scales,
    const float* __restrict__ opac, const float* __restrict__ Km,
    const float* __restrict__ Em, const float* __restrict__ spec,
    const float* __restrict__ tm, float* __restrict__ out)
{
  __shared__ __align__(16) float prm[N_G*8];     // rank-sorted hit params (16 KB)
  __shared__ __align__(16) float buf[CHUNK*64];  // keys during build; alpha (12 KB)
  __shared__ __align__(16) float sbuf[CHUNK*32]; // staged 30-ch rows (6 KB)
  __shared__ unsigned long long livem[4];
  __shared__ int wcnt[4];
  // total ~35 KB -> 4 blocks/CU (16 waves/CU)

  const int tid  = threadIdx.x;
  const int w    = tid >> 6;
  const int lane = tid & 63;
  const int tx = lane & 15, ty = lane >> 4;
  const unsigned long long ltm = (1ull << lane) - 1ull;

  const int t  = blockIdx.x >> 2;       // tile
  const int cq = blockIdx.x & 3;        // channel quarter

  // ---- prep: project 2 gaussians per thread into registers ----
  float psx[2], psy[2], pc00[2], pc11[2], pl2[2], pd[2];
  float bxmin[2], bxmax[2], bymin[2], bymax[2];
  {
    const float E0=Em[0],E1=Em[1],E2=Em[2],E3=Em[3],
                E4=Em[4],E5=Em[5],E6=Em[6],E7=Em[7],
                E8=Em[8],E9=Em[9],E10=Em[10],E11=Em[11];
    const float K0=Km[0],K1=Km[1],K2=Km[2],
                K3=Km[3],K4=Km[4],K5=Km[5],
                K6=Km[6],K7=Km[7],K8=Km[8];
    #pragma unroll
    for (int q = 0; q < 2; ++q) {
      const int g = w*128 + lane + q*64;           // original index (wave-major)
      float p0 = pos[g*3+0], p1 = pos[g*3+1], p2 = pos[g*3+2];
      float cam0 = E0*p0 + E1*p1 + E2*p2  + E3;
      float cam1 = E4*p0 + E5*p1 + E6*p2  + E7;
      float cam2 = E8*p0 + E9*p1 + E10*p2 + E11;
      float pr0 = K0*cam0 + K1*cam1 + K2*cam2;
      float pr1 = K3*cam0 + K4*cam1 + K5*cam2;
      float pr2 = K6*cam0 + K7*cam1 + K8*cam2;
      float inv = 1.0f/(pr2 + 1e-6f);
      float sx = pr0*inv, sy = pr1*inv;
      float depth = cam2;
      bool valid = (depth > 0.01f) && (depth < 100.0f)
                && (sx > -100.0f) && (sx < (float)IMG_W + 100.0f)
                && (sy > -100.0f) && (sy < (float)IMG_H + 100.0f);
      bool off = (sx < -(float)IMG_W) || (sx > 2.0f*(float)IMG_W)
              || (sy < -(float)IMG_H) || (sy > 2.0f*(float)IMG_H);
      bool skip = off || (!valid);
      float s0 = scales[g*3+0], s1 = scales[g*3+1];
      float v0 = s0*s0 + 1e-4f, v1 = s1*s1 + 1e-4f;
      const float HL2E = 0.72134752f;              // 0.5*log2(e)
      psx[q] = sx; psy[q] = sy;
      pc00[q] = HL2E/v0; pc11[q] = HL2E/v1;
      pl2[q] = __log2f(skip ? 0.0f : opac[g]);     // op=0 -> -inf -> exp2 -> 0
      pd[q]  = depth;
      float rx = 6.0f*sqrtf(v0);                   // mahal cutoff 36 (6 sigma)
      float ry = 6.0f*sqrtf(v1);
      bxmin[q] = skip ?  1e9f : sx - rx;
      bxmax[q] = skip ? -1e9f : sx + rx;
      bymin[q] = skip ?  1e9f : sy - ry;
      bymax[q] = skip ? -1e9f : sy + ry;
    }
  }

  // center-out bijection: heavy central tiles get the lowest blockIdx
  const int jx = t % TSX, ky = t / TSX;
  const int bx = 10 + ((jx & 1) ? ((jx+1)>>1) : -((jx+1)>>1));
  const int by = 40 + ((ky & 1) ? ((ky+1)>>1) : -((ky+1)>>1));

  const int x = bx*16 + tx;
  const int y = by*4 + ty;
  const bool inb = (x < IMG_W) && (y < IMG_H);
  const float px = (float)min(x, IMG_W-1);
  const float py = (float)min(y, IMG_H-1);
  const float wxmin = (float)(bx*16), wxmax = wxmin + 15.0f;
  const float wymin = (float)(by*4),  wymax = wymin + 3.0f;

  // ---- build: AABB + ellipse nearest-point prune, compaction, rank-sort ----
  bool h0 = !(bxmin[0] > wxmax || bxmax[0] < wxmin ||
              bymin[0] > wymax || bymax[0] < wymin);
  bool h1 = !(bxmin[1] > wxmax || bxmax[1] < wxmin ||
              bymin[1] > wymax || bymax[1] < wymin);
  {
    // nearest point of tile box to center; emax bounds e over all pixels
    float nx0 = fminf(fmaxf(psx[0], wxmin), wxmax);
    float ny0 = fminf(fmaxf(psy[0], wymin), wymax);
    float dx0 = nx0 - psx[0], dy0 = ny0 - psy[0];
    h0 = h0 && (pl2[0] - (pc00[0]*dx0*dx0 + pc11[0]*dy0*dy0) > -24.0f);
    float nx1 = fminf(fmaxf(psx[1], wxmin), wxmax);
    float ny1 = fminf(fmaxf(psy[1], wymin), wymax);
    float dx1 = nx1 - psx[1], dy1 = ny1 - psy[1];
    h1 = h1 && (pl2[1] - (pc00[1]*dx1*dx1 + pc11[1]*dy1*dy1) > -24.0f);
  }
  unsigned long long m0 = __ballot(h0), m1 = __ballot(h1);
  int c0 = __popcll(m0);
  if (lane == 0) wcnt[w] = c0 + __popcll(m1);
  __syncthreads();
  int offw = 0;
  #pragma unroll
  for (int k = 0; k < 4; ++k) if (k < w) offw += wcnt[k];
  const int nh = wcnt[0] + wcnt[1] + wcnt[2] + wcnt[3];
  // compacted depth keys (compaction order == original-index order)
  const int p0 = offw + __popcll(m0 & ltm);
  const int p1 = offw + c0 + __popcll(m1 & ltm);
  if (h0) buf[p0] = pd[0];
  if (h1) buf[p1] = pd[1];
  if (tid < 4) buf[nh + tid] = 1e30f;            // pad for float4 scan
  __syncthreads();

  // rank-scan (broadcast b128 reads); stable tie-break by compacted position
  if (h0 | h1) {
    int r0 = 0, r1 = 0;
    const float d0 = pd[0], d1 = pd[1];
    for (int j = 0; j < nh; j += 4) {
      float4 k4 = *(const float4*)&buf[j];
      if (h0) {
        r0 += (k4.x < d0 || (k4.x == d0 && j+0 < p0)) ? 1 : 0;
        r0 += (k4.y < d0 || (k4.y == d0 && j+1 < p0)) ? 1 : 0;
        r0 += (k4.z < d0 || (k4.z == d0 && j+2 < p0)) ? 1 : 0;
        r0 += (k4.w < d0 || (k4.w == d0 && j+3 < p0)) ? 1 : 0;
      }
      if (h1) {
        r1 += (k4.x < d1 || (k4.x == d1 && j+0 < p1)) ? 1 : 0;
        r1 += (k4.y < d1 || (k4.y == d1 && j+1 < p1)) ? 1 : 0;
        r1 += (k4.z < d1 || (k4.z == d1 && j+2 < p1)) ? 1 : 0;
        r1 += (k4.w < d1 || (k4.w == d1 && j+3 < p1)) ? 1 : 0;
      }
    }
    if (h0) {
      *(float4*)&prm[r0*8]   = make_float4(psx[0], psy[0], pc00[0], pc11[0]);
      *(float4*)&prm[r0*8+4] = make_float4(pl2[0], pd[0],
                                 __int_as_float((w*128 + lane)*N_C), 0.0f);
    }
    if (h1) {
      *(float4*)&prm[r1*8]   = make_float4(psx[1], psy[1], pc00[1], pc11[1]);
      *(float4*)&prm[r1*8+4] = make_float4(pl2[1], pd[1],
                                 __int_as_float((w*128 + lane + 64)*N_C), 0.0f);
    }
  }
  __syncthreads();

  float T = 1.0f, dacc = 0.0f;          // T bitwise-identical across waves
  float4 acc0 = {0,0,0,0}, acc1 = {0,0,0,0};   // groups g0 = cq+8w, g1 = g0+4
  const int g0 = cq + 8*w;
  const bool g1ok = (g0 + 4) < 30;
  // staging channel for lanes < 32: c = 16*(lane>>2) + 4*cq + (lane&3)
  const int stc = 16*(lane >> 2) + 4*cq + (lane & 3);
  const bool stok = (lane < 32) && (stc < N_C);

  for (int cb = 0; cb < nh; cb += CHUNK) {
    const int nc = min(CHUNK, nh - cb);

    // ---- phase A: alpha + liveness ballot + 30-ch staging (live rows) ----
    unsigned long long lm = 0;
    #pragma unroll 2
    for (int j = w; j < nc; j += 4) {
      float4 q0 = *(const float4*)&prm[(cb+j)*8];     // ds_read_b128
      float4 q1 = *(const float4*)&prm[(cb+j)*8+4];
      float dx = px - q0.x, dy = py - q0.y;
      float m = q0.z*dx*dx + q0.w*dy*dy;              // log2-units
      float e = q1.x - m;
      buf[j*64 + lane] = exp2f(e);                    // raw alpha
      unsigned long long bl = __ballot(e > -24.0f);   // alpha >= ~6e-8 anywhere?
      if (bl) {
        lm |= 1ull << j;
        int sbase = __float_as_int(q1.z);             // src*120
        if (stok) sbuf[j*32 + lane] = spec[sbase + stc];
      }
    }
    if (lane == 0) livem[w] = lm;
    __syncthreads();
    const unsigned long long mask = livem[0]|livem[1]|livem[2]|livem[3];

    // ---- phase B: per-wave fused T-chain + channel accumulation ----
    // (branch-free body: no counter, no mid-loop ballot - r8 lesson)
    unsigned long long m2 = mask;
    while (m2) {
      const int j = __builtin_ctzll(m2); m2 &= m2 - 1;
      float a  = buf[j*64 + lane];                    // conflict-free b32
      float wv = a * T;
      T *= (1.0f - a);
      if (w == 0)                                     // wave-uniform branch
        dacc = fmaf(prm[(cb+j)*8+5], wv, dacc);       // depth (used by cq2)
      const float* row = &sbuf[j*32 + 8*w];           // uniform b128 reads
      float4 s0 = *(const float4*)(row);
      acc0.x = fmaf(wv, s0.x, acc0.x);
      acc0.y = fmaf(wv, s0.y, acc0.y);
      acc0.z = fmaf(wv, s0.z, acc0.z);
      acc0.w = fmaf(wv, s0.w, acc0.w);
      if (g1ok) {
        float4 s1 = *(const float4*)(row + 4);
        acc1.x = fmaf(wv, s1.x, acc1.x);
        acc1.y = fmaf(wv, s1.y, acc1.y);
        acc1.z = fmaf(wv, s1.z, acc1.z);
        acc1.w = fmaf(wv, s1.w, acc1.w);
      }
    }
    __syncthreads();   // buf/sbuf reused next chunk
    // early stop: T bitwise-identical across waves -> uniform branch (safe)
    if (!__ballot(T >= 1e-5f)) break;  // front-to-back: remainder <= T
  }

  // ---- epilogue: store wave-exclusive channel groups (no combine) ----
  if (inb) {
    const int pixi = y*IMG_W + x;
    const float bgT = T;                // BG*(1 - A_final), BG = 1.0
    float4 t0 = *(const float4*)&tm[4*g0];
    out[(4*g0+0)*HW + pixi] = (acc0.x + bgT)*t0.x;
    out[(4*g0+1)*HW + pixi] = (acc0.y + bgT)*t0.y;
    out[(4*g0+2)*HW + pixi] = (acc0.z + bgT)*t0.z;
    out[(4*g0+3)*HW + pixi] = (acc0.w + bgT)*t0.w;
    if (g1ok) {
      const int g1 = g0 + 4;
      float4 t1 = *(const float4*)&tm[4*g1];
      out[(4*g1+0)*HW + pixi] = (acc1.x + bgT)*t1.x;
      out[(4*g1+1)*HW + pixi] = (acc1.y + bgT)*t1.y;
      out[(4*g1+2)*HW + pixi] = (acc1.z + bgT)*t1.z;
      out[(4*g1+3)*HW + pixi] = (acc1.w + bgT)*t1.w;
    }
    if (cq == 2 && w == 0) out[N_C*HW + pixi] = dacc;          // depth
    if (cq == 3 && w == 0) out[N_C*HW + HW + pixi] = 1.0f - T; // A_final
  }
}

extern "C" void kernel_launch(void* const* d_in, const int* in_sizes, int n_in,
                              void* d_out, int out_size, void* d_ws, size_t ws_size,
                              hipStream_t stream) {
  const float* pos    = (const float*)d_in[0];
  // d_in[1] rotations: unused by the reference
  const float* scales = (const float*)d_in[2];
  const float* opac   = (const float*)d_in[3];
  const float* spec   = (const float*)d_in[4];
  const float* tm     = (const float*)d_in[5];
  const float* K      = (const float*)d_in[6];
  const float* E      = (const float*)d_in[7];
  float* out = (float*)d_out;
  (void)d_ws; (void)ws_size;   // no workspace needed

  k_render<<<NBLK, 256, 0, stream>>>(pos, scales, opac, K, E, spec, tm, out);
}

// Round 10
// 109.825 us; speedup vs baseline: 1.0404x; 1.0342x over previous
//
#include <hip/hip_runtime.h>
#include <math.h>

#define N_G 512
#define IMG_H 324
#define IMG_W 332
#define N_C 120
#define HW (IMG_H*IMG_W)
#define CHUNK 48               // 4 blocks/CU
#define TSX 21                 // tiles in x (16 px)
#define TSY 81                 // tiles in y (4 px)
#define NT (TSX*TSY)
#define NBLK (NT*4)            // 4 channel-split blocks per tile

// Round-9 structure with phase B converted to a BRANCH-FREE COUNTED loop.
// Rationale: the ellipse nearest-point prune at build applies the same -24
// log2-alpha threshold as phase A's per-row liveness ballot, so surviving
// rows are ~always live; the ctz mask-walk only destroyed ILP (each
// iteration's LDS address depended on the previous mask update -> no
// unrolling, one outstanding ds_read, ~120cy latency exposed; R8 counters:
// VALUBusy 51% @ 31% occupancy = half-latency-stalled). Counted loop has
// affine addresses -> compiler unrolls and batches ds_reads.
// Near-dead rows now multiply into T: a <= 2^-24, error < 1e-7 << 3.9e-3.

__global__ __launch_bounds__(256, 4) void k_render(
    const float* __restrict__ pos, const float* __restrict__ scales,
    const float* __restrict__ opac, const float* __restrict__ Km,
    const float* __restrict__ Em, const float* __restrict__ spec,
    const float* __restrict__ tm, float* __restrict__ out)
{
  __shared__ __align__(16) float prm[N_G*8];     // rank-sorted hit params (16 KB)
  __shared__ __align__(16) float buf[CHUNK*64];  // keys during build; alpha (12 KB)
  __shared__ __align__(16) float sbuf[CHUNK*32]; // staged 30-ch rows (6 KB)
  __shared__ int wcnt[4];
  // total ~34 KB -> 4 blocks/CU (16 waves/CU)

  const int tid  = threadIdx.x;
  const int w    = tid >> 6;
  const int lane = tid & 63;
  const int tx = lane & 15, ty = lane >> 4;
  const unsigned long long ltm = (1ull << lane) - 1ull;

  const int t  = blockIdx.x >> 2;       // tile
  const int cq = blockIdx.x & 3;        // channel quarter

  // ---- prep: project 2 gaussians per thread into registers ----
  float psx[2], psy[2], pc00[2], pc11[2], pl2[2], pd[2];
  float bxmin[2], bxmax[2], bymin[2], bymax[2];
  {
    const float E0=Em[0],E1=Em[1],E2=Em[2],E3=Em[3],
                E4=Em[4],E5=Em[5],E6=Em[6],E7=Em[7],
                E8=Em[8],E9=Em[9],E10=Em[10],E11=Em[11];
    const float K0=Km[0],K1=Km[1],K2=Km[2],
                K3=Km[3],K4=Km[4],K5=Km[5],
                K6=Km[6],K7=Km[7],K8=Km[8];
    #pragma unroll
    for (int q = 0; q < 2; ++q) {
      const int g = w*128 + lane + q*64;           // original index (wave-major)
      float p0 = pos[g*3+0], p1 = pos[g*3+1], p2 = pos[g*3+2];
      float cam0 = E0*p0 + E1*p1 + E2*p2  + E3;
      float cam1 = E4*p0 + E5*p1 + E6*p2  + E7;
      float cam2 = E8*p0 + E9*p1 + E10*p2 + E11;
      float pr0 = K0*cam0 + K1*cam1 + K2*cam2;
      float pr1 = K3*cam0 + K4*cam1 + K5*cam2;
      float pr2 = K6*cam0 + K7*cam1 + K8*cam2;
      float inv = 1.0f/(pr2 + 1e-6f);
      float sx = pr0*inv, sy = pr1*inv;
      float depth = cam2;
      bool valid = (depth > 0.01f) && (depth < 100.0f)
                && (sx > -100.0f) && (sx < (float)IMG_W + 100.0f)
                && (sy > -100.0f) && (sy < (float)IMG_H + 100.0f);
      bool off = (sx < -(float)IMG_W) || (sx > 2.0f*(float)IMG_W)
              || (sy < -(float)IMG_H) || (sy > 2.0f*(float)IMG_H);
      bool skip = off || (!valid);
      float s0 = scales[g*3+0], s1 = scales[g*3+1];
      float v0 = s0*s0 + 1e-4f, v1 = s1*s1 + 1e-4f;
      const float HL2E = 0.72134752f;              // 0.5*log2(e)
      psx[q] = sx; psy[q] = sy;
      pc00[q] = HL2E/v0; pc11[q] = HL2E/v1;
      pl2[q] = __log2f(skip ? 0.0f : opac[g]);     // op=0 -> -inf -> exp2 -> 0
      pd[q]  = depth;
      float rx = 6.0f*sqrtf(v0);                   // mahal cutoff 36 (6 sigma)
      float ry = 6.0f*sqrtf(v1);
      bxmin[q] = skip ?  1e9f : sx - rx;
      bxmax[q] = skip ? -1e9f : sx + rx;
      bymin[q] = skip ?  1e9f : sy - ry;
      bymax[q] = skip ? -1e9f : sy + ry;
    }
  }

  // center-out bijection: heavy central tiles get the lowest blockIdx
  const int jx = t % TSX, ky = t / TSX;
  const int bx = 10 + ((jx & 1) ? ((jx+1)>>1) : -((jx+1)>>1));
  const int by = 40 + ((ky & 1) ? ((ky+1)>>1) : -((ky+1)>>1));

  const int x = bx*16 + tx;
  const int y = by*4 + ty;
  const bool inb = (x < IMG_W) && (y < IMG_H);
  const float px = (float)min(x, IMG_W-1);
  const float py = (float)min(y, IMG_H-1);
  const float wxmin = (float)(bx*16), wxmax = wxmin + 15.0f;
  const float wymin = (float)(by*4),  wymax = wymin + 3.0f;

  // ---- build: AABB + ellipse nearest-point prune, compaction, rank-sort ----
  bool h0 = !(bxmin[0] > wxmax || bxmax[0] < wxmin ||
              bymin[0] > wymax || bymax[0] < wymin);
  bool h1 = !(bxmin[1] > wxmax || bxmax[1] < wxmin ||
              bymin[1] > wymax || bymax[1] < wymin);
  {
    // nearest point of tile box to center; emax bounds e over all pixels
    float nx0 = fminf(fmaxf(psx[0], wxmin), wxmax);
    float ny0 = fminf(fmaxf(psy[0], wymin), wymax);
    float dx0 = nx0 - psx[0], dy0 = ny0 - psy[0];
    h0 = h0 && (pl2[0] - (pc00[0]*dx0*dx0 + pc11[0]*dy0*dy0) > -24.0f);
    float nx1 = fminf(fmaxf(psx[1], wxmin), wxmax);
    float ny1 = fminf(fmaxf(psy[1], wymin), wymax);
    float dx1 = nx1 - psx[1], dy1 = ny1 - psy[1];
    h1 = h1 && (pl2[1] - (pc00[1]*dx1*dx1 + pc11[1]*dy1*dy1) > -24.0f);
  }
  unsigned long long m0 = __ballot(h0), m1 = __ballot(h1);
  int c0 = __popcll(m0);
  if (lane == 0) wcnt[w] = c0 + __popcll(m1);
  __syncthreads();
  int offw = 0;
  #pragma unroll
  for (int k = 0; k < 4; ++k) if (k < w) offw += wcnt[k];
  const int nh = wcnt[0] + wcnt[1] + wcnt[2] + wcnt[3];
  // compacted depth keys (compaction order == original-index order)
  const int p0 = offw + __popcll(m0 & ltm);
  const int p1 = offw + c0 + __popcll(m1 & ltm);
  if (h0) buf[p0] = pd[0];
  if (h1) buf[p1] = pd[1];
  if (tid < 4) buf[nh + tid] = 1e30f;            // pad for float4 scan
  __syncthreads();

  // rank-scan (broadcast b128 reads); stable tie-break by compacted position
  if (h0 | h1) {
    int r0 = 0, r1 = 0;
    const float d0 = pd[0], d1 = pd[1];
    for (int j = 0; j < nh; j += 4) {
      float4 k4 = *(const float4*)&buf[j];
      if (h0) {
        r0 += (k4.x < d0 || (k4.x == d0 && j+0 < p0)) ? 1 : 0;
        r0 += (k4.y < d0 || (k4.y == d0 && j+1 < p0)) ? 1 : 0;
        r0 += (k4.z < d0 || (k4.z == d0 && j+2 < p0)) ? 1 : 0;
        r0 += (k4.w < d0 || (k4.w == d0 && j+3 < p0)) ? 1 : 0;
      }
      if (h1) {
        r1 += (k4.x < d1 || (k4.x == d1 && j+0 < p1)) ? 1 : 0;
        r1 += (k4.y < d1 || (k4.y == d1 && j+1 < p1)) ? 1 : 0;
        r1 += (k4.z < d1 || (k4.z == d1 && j+2 < p1)) ? 1 : 0;
        r1 += (k4.w < d1 || (k4.w == d1 && j+3 < p1)) ? 1 : 0;
      }
    }
    if (h0) {
      *(float4*)&prm[r0*8]   = make_float4(psx[0], psy[0], pc00[0], pc11[0]);
      *(float4*)&prm[r0*8+4] = make_float4(pl2[0], pd[0],
                                 __int_as_float((w*128 + lane)*N_C), 0.0f);
    }
    if (h1) {
      *(float4*)&prm[r1*8]   = make_float4(psx[1], psy[1], pc00[1], pc11[1]);
      *(float4*)&prm[r1*8+4] = make_float4(pl2[1], pd[1],
                                 __int_as_float((w*128 + lane + 64)*N_C), 0.0f);
    }
  }
  __syncthreads();

  float T = 1.0f, dacc = 0.0f;          // T bitwise-identical across waves
  float4 acc0 = {0,0,0,0}, acc1 = {0,0,0,0};   // groups g0 = cq+8w, g1 = g0+4
  const int g0 = cq + 8*w;
  const bool g1ok = (g0 + 4) < 30;
  // staging channel for lanes < 32: c = 16*(lane>>2) + 4*cq + (lane&3)
  const int stc = 16*(lane >> 2) + 4*cq + (lane & 3);
  const bool stok = (lane < 32) && (stc < N_C);

  for (int cb = 0; cb < nh; cb += CHUNK) {
    const int nc = min(CHUNK, nh - cb);

    // ---- phase A: alpha + unconditional 30-ch staging (rows ~all live) ----
    #pragma unroll 2
    for (int j = w; j < nc; j += 4) {
      float4 q0 = *(const float4*)&prm[(cb+j)*8];     // ds_read_b128
      float4 q1 = *(const float4*)&prm[(cb+j)*8+4];
      float dx = px - q0.x, dy = py - q0.y;
      float m = q0.z*dx*dx + q0.w*dy*dy;              // log2-units
      buf[j*64 + lane] = exp2f(q1.x - m);             // raw alpha
      int sbase = __float_as_int(q1.z);               // src*120
      if (stok) sbuf[j*32 + lane] = spec[sbase + stc];
    }
    __syncthreads();

    // ---- phase B: branch-free counted loop (affine LDS addresses) ----
    #pragma unroll 2
    for (int j = 0; j < nc; ++j) {
      float a  = buf[j*64 + lane];                    // conflict-free b32
      float wv = a * T;
      T *= (1.0f - a);
      if (w == 0)                                     // wave-uniform branch
        dacc = fmaf(prm[(cb+j)*8+5], wv, dacc);       // depth (used by cq2)
      const float* row = &sbuf[j*32 + 8*w];           // uniform b128 reads
      float4 s0 = *(const float4*)(row);
      acc0.x = fmaf(wv, s0.x, acc0.x);
      acc0.y = fmaf(wv, s0.y, acc0.y);
      acc0.z = fmaf(wv, s0.z, acc0.z);
      acc0.w = fmaf(wv, s0.w, acc0.w);
      if (g1ok) {
        float4 s1 = *(const float4*)(row + 4);
        acc1.x = fmaf(wv, s1.x, acc1.x);
        acc1.y = fmaf(wv, s1.y, acc1.y);
        acc1.z = fmaf(wv, s1.z, acc1.z);
        acc1.w = fmaf(wv, s1.w, acc1.w);
      }
    }
    __syncthreads();   // buf/sbuf reused next chunk
    // early stop: T bitwise-identical across waves -> uniform branch (safe)
    if (!__ballot(T >= 1e-5f)) break;  // front-to-back: remainder <= T
  }

  // ---- epilogue: store wave-exclusive channel groups (no combine) ----
  if (inb) {
    const int pixi = y*IMG_W + x;
    const float bgT = T;                // BG*(1 - A_final), BG = 1.0
    float4 t0 = *(const float4*)&tm[4*g0];
    out[(4*g0+0)*HW + pixi] = (acc0.x + bgT)*t0.x;
    out[(4*g0+1)*HW + pixi] = (acc0.y + bgT)*t0.y;
    out[(4*g0+2)*HW + pixi] = (acc0.z + bgT)*t0.z;
    out[(4*g0+3)*HW + pixi] = (acc0.w + bgT)*t0.w;
    if (g1ok) {
      const int g1 = g0 + 4;
      float4 t1 = *(const float4*)&tm[4*g1];
      out[(4*g1+0)*HW + pixi] = (acc1.x + bgT)*t1.x;
      out[(4*g1+1)*HW + pixi] = (acc1.y + bgT)*t1.y;
      out[(4*g1+2)*HW + pixi] = (acc1.z + bgT)*t1.z;
      out[(4*g1+3)*HW + pixi] = (acc1.w + bgT)*t1.w;
    }
    if (cq == 2 && w == 0) out[N_C*HW + pixi] = dacc;          // depth
    if (cq == 3 && w == 0) out[N_C*HW + HW + pixi] = 1.0f - T; // A_final
  }
}

extern "C" void kernel_launch(void* const* d_in, const int* in_sizes, int n_in,
                              void* d_out, int out_size, void* d_ws, size_t ws_size,
                              hipStream_t stream) {
  const float* pos    = (const float*)d_in[0];
  // d_in[1] rotations: unused by the reference
  const float* scales = (const float*)d_in[2];
  const float* opac   = (const float*)d_in[3];
  const float* spec   = (const float*)d_in[4];
  const float* tm     = (const float*)d_in[5];
  const float* K      = (const float*)d_in[6];
  const float* E      = (const float*)d_in[7];
  float* out = (float*)d_out;
  (void)d_ws; (void)ws_size;   // no workspace needed

  k_render<<<NBLK, 256, 0, stream>>>(pos, scales, opac, K, E, spec, tm, out);
}